// Round 29
// baseline (149.547 us; speedup 1.0000x reference)
//
#include <hip/hip_runtime.h>
#include <math.h>

#define NN 102400
#define D 256
#define B 2048

typedef __bf16 bf16x8 __attribute__((ext_vector_type(8)));
typedef float f32x4 __attribute__((ext_vector_type(4)));

// K1: anchor + own bounds. Measured 15.7us/pass (R23 x8) = 6.4 TB/s — at roofline.
// R29: thread 2 of block 0 resets the attn work-stealing counter to 2048
// (first 2048 items are statically assigned; counter feeds the rest).
__global__ __launch_bounds__(256)
void k_anchor3(const float* __restrict__ ifeat, const int* __restrict__ seg,
               float* __restrict__ out, float* __restrict__ anc_buf,
               int* __restrict__ seg_start, int* __restrict__ work_ctr) {
    __shared__ int sb[2];
    __shared__ float red[4][256];
    int b = blockIdx.x;
    int t = threadIdx.x;
    if (b == 0 && t == 2) work_ctr[0] = 2048;
    if (t < 2) {
        int target = b + t;
        int lo = 0, hi = NN;
        while (lo < hi) { int mid = (lo + hi) >> 1; if (seg[mid] < target) lo = mid + 1; else hi = mid; }
        sb[t] = lo;
        if (t == 0) seg_start[b] = lo;
        if (t == 1 && b == B - 1) seg_start[B] = lo;
    }
    __syncthreads();
    int w = t >> 6, l = t & 63;
    int s = sb[0], e = sb[1];
    const float* bp = ifeat + (size_t)l * 4;
    float4 a0 = make_float4(0.f, 0.f, 0.f, 0.f), a1 = a0, a2 = a0, a3 = a0, a4 = a0, a5 = a0;
    int i = s + w;
    for (; i + 20 < e; i += 24) {
        float4 v0 = *(const float4*)(bp + (size_t)(i +  0) * D);
        float4 v1 = *(const float4*)(bp + (size_t)(i +  4) * D);
        float4 v2 = *(const float4*)(bp + (size_t)(i +  8) * D);
        float4 v3 = *(const float4*)(bp + (size_t)(i + 12) * D);
        float4 v4 = *(const float4*)(bp + (size_t)(i + 16) * D);
        float4 v5 = *(const float4*)(bp + (size_t)(i + 20) * D);
        a0.x += v0.x; a0.y += v0.y; a0.z += v0.z; a0.w += v0.w;
        a1.x += v1.x; a1.y += v1.y; a1.z += v1.z; a1.w += v1.w;
        a2.x += v2.x; a2.y += v2.y; a2.z += v2.z; a2.w += v2.w;
        a3.x += v3.x; a3.y += v3.y; a3.z += v3.z; a3.w += v3.w;
        a4.x += v4.x; a4.y += v4.y; a4.z += v4.z; a4.w += v4.w;
        a5.x += v5.x; a5.y += v5.y; a5.z += v5.z; a5.w += v5.w;
    }
    for (; i < e; i += 4) {
        float4 v = *(const float4*)(bp + (size_t)i * D);
        a0.x += v.x; a0.y += v.y; a0.z += v.z; a0.w += v.w;
    }
    float4 acc = make_float4(((a0.x + a1.x) + (a2.x + a3.x)) + (a4.x + a5.x),
                             ((a0.y + a1.y) + (a2.y + a3.y)) + (a4.y + a5.y),
                             ((a0.z + a1.z) + (a2.z + a3.z)) + (a4.z + a5.z),
                             ((a0.w + a1.w) + (a2.w + a3.w)) + (a4.w + a5.w));
    *(float4*)&red[w][l * 4] = acc;
    __syncthreads();
    float sum = (red[0][t] + red[1][t]) + (red[2][t] + red[3][t]);
    int cnt = e - s;
    float inv = 1.0f / (float)(cnt > 0 ? cnt : 1);
    float v = sum * inv;
    out[(size_t)b * 512 + 256 + t] = v;
    anc_buf[(size_t)b * D + t] = v;
}

// K2 (MFMA featv): writes feat_v TRANSPOSED (R24): fvT[seg*256 + (j&15)*16 + (j>>4)].
__global__ __launch_bounds__(256)
void k_featv3(const float* __restrict__ anc_buf, const float* __restrict__ Wv,
              const float* __restrict__ bv, float* __restrict__ fvT) {
    __shared__ __bf16 As[16][264];   // 256 + 8 pad
    int b0 = blockIdx.x * 16;
    int t = threadIdx.x;
    int lane = t & 63, w = t >> 6;
    int ln15 = lane & 15, lg = lane >> 4;
#pragma unroll
    for (int r = 0; r < 16; ++r) As[r][t] = (__bf16)anc_buf[(size_t)(b0 + r) * D + t];
    __syncthreads();
    bf16x8 afr[8];
#pragma unroll
    for (int kc = 0; kc < 8; ++kc) afr[kc] = *(const bf16x8*)&As[ln15][kc * 32 + lg * 8];
#pragma unroll
    for (int q = 0; q < 4; ++q) {
        int jt = w * 4 + q;                   // j = jt*16 + ln15
        f32x4 acc = (f32x4){0.f, 0.f, 0.f, 0.f};
#pragma unroll
        for (int kc = 0; kc < 8; ++kc) {
            const float* wp = Wv + (size_t)(jt * 16 + ln15) * D + kc * 32 + lg * 8;
            float4 p = *(const float4*)(wp);
            float4 r4 = *(const float4*)(wp + 4);
            bf16x8 bfr;
            bfr[0] = (__bf16)p.x;  bfr[1] = (__bf16)p.y;  bfr[2] = (__bf16)p.z;  bfr[3] = (__bf16)p.w;
            bfr[4] = (__bf16)r4.x; bfr[5] = (__bf16)r4.y; bfr[6] = (__bf16)r4.z; bfr[7] = (__bf16)r4.w;
            acc = __builtin_amdgcn_mfma_f32_16x16x32_bf16(afr[kc], bfr, acc, 0, 0, 0);
        }
        float bvj = bv[jt * 16 + ln15];
#pragma unroll
        for (int r = 0; r < 4; ++r) {
            fvT[(size_t)(b0 + lg * 4 + r) * 256 + ln15 * 16 + jt] = acc[r] + bvj;
        }
    }
}

// K3 (MFMA attn, R29): R28 base (94.1us best) + DYNAMIC WORK-STEALING.
// Static balanced map still leaves the worst SIMD at 7 item-units vs 6.25 avg
// (~12% tail). Each wave: first item static (wgid — avoids a 2048-pop burst),
// then lane-0 atomicAdd pops (4352 total ~ 1/17cyc chip-wide, overlapped with
// ~14Kcyc items). Output deterministic: each item writes only its own rows.
__global__ __launch_bounds__(512, 1)
void k_attn_e_mfma(const float* __restrict__ ifeat, const float* __restrict__ Wu,
                   const float* __restrict__ fvT, const float* __restrict__ we,
                   const int* __restrict__ seg_ids, float* __restrict__ e_out,
                   int* __restrict__ work_ctr) {
    __shared__ __bf16 Bs[256 * 256];   // 128 KB; row j stride 512 B; byte ^= (j&7)<<4

    int tx = threadIdx.x;
    int lane = tx & 63;
    int w = tx >> 6;                   // 0..7
    int ln15 = lane & 15;
    int lg = lane >> 4;

    // ---- stage full Wu: thread -> (row jl=tx>>1, k-half kh=tx&1), 128 elems ----
    {
        int jl = tx >> 1, kh = tx & 1;
        const float* wp = Wu + (size_t)jl * D + kh * 128;
        char* rowp = (char*)Bs + jl * 512;
        int sw = (jl & 7) << 4;
#pragma unroll
        for (int q = 0; q < 16; ++q) {
            float4 b0 = *(const float4*)(wp + q * 8);
            float4 b1 = *(const float4*)(wp + q * 8 + 4);
            bf16x8 v;
            v[0] = (__bf16)b0.x; v[1] = (__bf16)b0.y; v[2] = (__bf16)b0.z; v[3] = (__bf16)b0.w;
            v[4] = (__bf16)b1.x; v[5] = (__bf16)b1.y; v[6] = (__bf16)b1.z; v[7] = (__bf16)b1.w;
            *(bf16x8*)(rowp + ((kh * 256 + q * 16) ^ sw)) = v;
        }
    }
    __syncthreads();

    int swr = (ln15 & 7) << 4;
    int klo = lg * 16;
    const char* bbase = (const char*)Bs + ln15 * 512;
    const float* weh  = we + ln15;

    int item = blockIdx.x + 256 * w;         // first item: static balanced map

    while (item < NN / 16) {
        int nb = item * 16;
        int r0 = nb + lg * 4;

        // ---- prefetch epilogue fv: 4 rows x 4 float4 (transposed layout) ----
        const float* q0 = fvT + (size_t)seg_ids[r0 + 0] * 256 + ln15 * 16;
        const float* q1 = fvT + (size_t)seg_ids[r0 + 1] * 256 + ln15 * 16;
        const float* q2 = fvT + (size_t)seg_ids[r0 + 2] * 256 + ln15 * 16;
        const float* q3 = fvT + (size_t)seg_ids[r0 + 3] * 256 + ln15 * 16;
        float4 fvA0 = *(const float4*)(q0 +  0), fvA1 = *(const float4*)(q0 +  4),
               fvA2 = *(const float4*)(q0 +  8), fvA3 = *(const float4*)(q0 + 12);
        float4 fvB0 = *(const float4*)(q1 +  0), fvB1 = *(const float4*)(q1 +  4),
               fvB2 = *(const float4*)(q1 +  8), fvB3 = *(const float4*)(q1 + 12);
        float4 fvC0 = *(const float4*)(q2 +  0), fvC1 = *(const float4*)(q2 +  4),
               fvC2 = *(const float4*)(q2 +  8), fvC3 = *(const float4*)(q2 + 12);
        float4 fvD0 = *(const float4*)(q3 +  0), fvD1 = *(const float4*)(q3 +  4),
               fvD2 = *(const float4*)(q3 +  8), fvD3 = *(const float4*)(q3 + 12);

        const float* ap = ifeat + (size_t)(nb + ln15) * D + lg * 8;

        f32x4 a0 = (f32x4){0.f,0.f,0.f,0.f}, a1 = a0, a2 = a0, a3 = a0,
              a4 = a0, a5 = a0, a6 = a0, a7 = a0,
              a8 = a0, a9 = a0, a10 = a0, a11 = a0,
              a12 = a0, a13 = a0, a14 = a0, a15 = a0;

        // ---- 3-deep rolling A pipeline (named regs, static indices) ----
        float4 xc = *(const float4*)(ap +  0), yc = *(const float4*)(ap +  4);
        float4 x1 = *(const float4*)(ap + 32), y1 = *(const float4*)(ap + 36);
        float4 x2 = *(const float4*)(ap + 64), y2 = *(const float4*)(ap + 68);
#pragma unroll 1
        for (int ch = 0; ch < 8; ++ch) {
            int nx = ((ch + 3) & 7) * 32;              // wrap: last 3 iters re-read 0..2 (L1-hot)
            float4 x3 = *(const float4*)(ap + nx);
            float4 y3 = *(const float4*)(ap + nx + 4);
            bf16x8 af;
            af[0] = (__bf16)xc.x; af[1] = (__bf16)xc.y; af[2] = (__bf16)xc.z; af[3] = (__bf16)xc.w;
            af[4] = (__bf16)yc.x; af[5] = (__bf16)yc.y; af[6] = (__bf16)yc.z; af[7] = (__bf16)yc.w;
            int kb = (ch * 64 + klo) ^ swr;
            __builtin_amdgcn_s_setprio(1);
            a0  = __builtin_amdgcn_mfma_f32_16x16x32_bf16(af, *(const bf16x8*)(bbase +  0 * 8192 + kb), a0,  0, 0, 0);
            a1  = __builtin_amdgcn_mfma_f32_16x16x32_bf16(af, *(const bf16x8*)(bbase +  1 * 8192 + kb), a1,  0, 0, 0);
            a2  = __builtin_amdgcn_mfma_f32_16x16x32_bf16(af, *(const bf16x8*)(bbase +  2 * 8192 + kb), a2,  0, 0, 0);
            a3  = __builtin_amdgcn_mfma_f32_16x16x32_bf16(af, *(const bf16x8*)(bbase +  3 * 8192 + kb), a3,  0, 0, 0);
            a4  = __builtin_amdgcn_mfma_f32_16x16x32_bf16(af, *(const bf16x8*)(bbase +  4 * 8192 + kb), a4,  0, 0, 0);
            a5  = __builtin_amdgcn_mfma_f32_16x16x32_bf16(af, *(const bf16x8*)(bbase +  5 * 8192 + kb), a5,  0, 0, 0);
            a6  = __builtin_amdgcn_mfma_f32_16x16x32_bf16(af, *(const bf16x8*)(bbase +  6 * 8192 + kb), a6,  0, 0, 0);
            a7  = __builtin_amdgcn_mfma_f32_16x16x32_bf16(af, *(const bf16x8*)(bbase +  7 * 8192 + kb), a7,  0, 0, 0);
            a8  = __builtin_amdgcn_mfma_f32_16x16x32_bf16(af, *(const bf16x8*)(bbase +  8 * 8192 + kb), a8,  0, 0, 0);
            a9  = __builtin_amdgcn_mfma_f32_16x16x32_bf16(af, *(const bf16x8*)(bbase +  9 * 8192 + kb), a9,  0, 0, 0);
            a10 = __builtin_amdgcn_mfma_f32_16x16x32_bf16(af, *(const bf16x8*)(bbase + 10 * 8192 + kb), a10, 0, 0, 0);
            a11 = __builtin_amdgcn_mfma_f32_16x16x32_bf16(af, *(const bf16x8*)(bbase + 11 * 8192 + kb), a11, 0, 0, 0);
            a12 = __builtin_amdgcn_mfma_f32_16x16x32_bf16(af, *(const bf16x8*)(bbase + 12 * 8192 + kb), a12, 0, 0, 0);
            a13 = __builtin_amdgcn_mfma_f32_16x16x32_bf16(af, *(const bf16x8*)(bbase + 13 * 8192 + kb), a13, 0, 0, 0);
            a14 = __builtin_amdgcn_mfma_f32_16x16x32_bf16(af, *(const bf16x8*)(bbase + 14 * 8192 + kb), a14, 0, 0, 0);
            a15 = __builtin_amdgcn_mfma_f32_16x16x32_bf16(af, *(const bf16x8*)(bbase + 15 * 8192 + kb), a15, 0, 0, 0);
            __builtin_amdgcn_s_setprio(0);
            xc = x1; yc = y1; x1 = x2; y1 = y2; x2 = x3; y2 = y3;
        }

        float part0 = 0.f, part1 = 0.f, part2 = 0.f, part3 = 0.f;

#define EPI(AC, CT, FQ, FC) { \
    float w_ = weh[(CT) * 16]; \
    part0 += w_ * __builtin_amdgcn_rcpf(1.f + __expf(-(AC[0] + fvA##FQ.FC))); \
    part1 += w_ * __builtin_amdgcn_rcpf(1.f + __expf(-(AC[1] + fvB##FQ.FC))); \
    part2 += w_ * __builtin_amdgcn_rcpf(1.f + __expf(-(AC[2] + fvC##FQ.FC))); \
    part3 += w_ * __builtin_amdgcn_rcpf(1.f + __expf(-(AC[3] + fvD##FQ.FC))); }

        EPI(a0,  0, 0, x) EPI(a1,  1, 0, y) EPI(a2,  2, 0, z) EPI(a3,  3, 0, w)
        EPI(a4,  4, 1, x) EPI(a5,  5, 1, y) EPI(a6,  6, 1, z) EPI(a7,  7, 1, w)
        EPI(a8,  8, 2, x) EPI(a9,  9, 2, y) EPI(a10, 10, 2, z) EPI(a11, 11, 2, w)
        EPI(a12, 12, 3, x) EPI(a13, 13, 3, y) EPI(a14, 14, 3, z) EPI(a15, 15, 3, w)
#undef EPI

#pragma unroll
        for (int off = 8; off >= 1; off >>= 1) {
            part0 += __shfl_xor(part0, off, 64);
            part1 += __shfl_xor(part1, off, 64);
            part2 += __shfl_xor(part2, off, 64);
            part3 += __shfl_xor(part3, off, 64);
        }
        if (ln15 == 0) {
            float4 o = make_float4(part0, part1, part2, part3);
            *(float4*)&e_out[r0] = o;
        }

        // ---- pop next item (wave-uniform) ----
        int nxt;
        if (lane == 0) nxt = atomicAdd(work_ctr, 1);
        nxt = __shfl(nxt, 0, 64);
        item = nxt;
    }
}

// K4: segment softmax + weighted sum. UNCHANGED.
__global__ void k_softmax_rst(const float* __restrict__ ifeat, const int* __restrict__ seg_start,
                              const float* __restrict__ e, float* __restrict__ out) {
    int b = blockIdx.x;
    int t = threadIdx.x; // 256
    int w = t >> 6, l = t & 63;
    int s = seg_start[b], en = seg_start[b + 1];
    float m = -1e30f;
    for (int i = s + t; i < en; i += 256) m = fmaxf(m, e[i]);
#pragma unroll
    for (int off = 32; off >= 1; off >>= 1) m = fmaxf(m, __shfl_xor(m, off, 64));
    __shared__ float red[4];
    if ((t & 63) == 0) red[t >> 6] = m;
    __syncthreads();
    float mall = fmaxf(fmaxf(red[0], red[1]), fmaxf(red[2], red[3]));
    float dsum = 0.f;
    for (int i = s + t; i < en; i += 256) dsum += __expf(e[i] - mall);
#pragma unroll
    for (int off = 32; off >= 1; off >>= 1) dsum += __shfl_xor(dsum, off, 64);
    __shared__ float red2[4];
    if ((t & 63) == 0) red2[t >> 6] = dsum;
    __syncthreads();
    float denom = red2[0] + red2[1] + red2[2] + red2[3];
    float invd = (en > s) ? 1.0f / denom : 0.f;

    const float* bp = ifeat + (size_t)l * 4;
    float4 c0 = make_float4(0.f, 0.f, 0.f, 0.f), c1 = c0, c2 = c0, c3 = c0, c4 = c0, c5 = c0;
    int i = s + w;
    for (; i + 20 < en; i += 24) {
        float al0 = __expf(e[i +  0] - mall) * invd;
        float al1 = __expf(e[i +  4] - mall) * invd;
        float al2 = __expf(e[i +  8] - mall) * invd;
        float al3 = __expf(e[i + 12] - mall) * invd;
        float al4 = __expf(e[i + 16] - mall) * invd;
        float al5 = __expf(e[i + 20] - mall) * invd;
        float4 v0 = *(const float4*)(bp + (size_t)(i +  0) * D);
        float4 v1 = *(const float4*)(bp + (size_t)(i +  4) * D);
        float4 v2 = *(const float4*)(bp + (size_t)(i +  8) * D);
        float4 v3 = *(const float4*)(bp + (size_t)(i + 12) * D);
        float4 v4 = *(const float4*)(bp + (size_t)(i + 16) * D);
        float4 v5 = *(const float4*)(bp + (size_t)(i + 20) * D);
        c0.x += v0.x * al0; c0.y += v0.y * al0; c0.z += v0.z * al0; c0.w += v0.w * al0;
        c1.x += v1.x * al1; c1.y += v1.y * al1; c1.z += v1.z * al1; c1.w += v1.w * al1;
        c2.x += v2.x * al2; c2.y += v2.y * al2; c2.z += v2.z * al2; c2.w += v2.w * al2;
        c3.x += v3.x * al3; c3.y += v3.y * al3; c3.z += v3.z * al3; c3.w += v3.w * al3;
        c4.x += v4.x * al4; c4.y += v4.y * al4; c4.z += v4.z * al4; c4.w += v4.w * al4;
        c5.x += v5.x * al5; c5.y += v5.y * al5; c5.z += v5.z * al5; c5.w += v5.w * al5;
    }
    for (; i < en; i += 4) {
        float al = __expf(e[i] - mall) * invd;
        float4 v = *(const float4*)(bp + (size_t)i * D);
        c0.x += v.x * al; c0.y += v.y * al; c0.z += v.z * al; c0.w += v.w * al;
    }
    float4 acc = make_float4(((c0.x + c1.x) + (c2.x + c3.x)) + (c4.x + c5.x),
                             ((c0.y + c1.y) + (c2.y + c3.y)) + (c4.y + c5.y),
                             ((c0.z + c1.z) + (c2.z + c3.z)) + (c4.z + c5.z),
                             ((c0.w + c1.w) + (c2.w + c3.w)) + (c4.w + c5.w));
    __shared__ float red3[4][256];
    *(float4*)&red3[w][l * 4] = acc;
    __syncthreads();
    out[(size_t)b * 512 + t] = (red3[0][t] + red3[1][t]) + (red3[2][t] + red3[3][t]);
}

extern "C" void kernel_launch(void* const* d_in, const int* in_sizes, int n_in,
                              void* d_out, int out_size, void* d_ws, size_t ws_size,
                              hipStream_t stream) {
    const float* ifeat = (const float*)d_in[0];
    const float* Wu    = (const float*)d_in[1];
    const float* Wv    = (const float*)d_in[2];
    const float* bv    = (const float*)d_in[3];
    const float* we    = (const float*)d_in[4];
    const int*   seg   = (const int*)d_in[5];
    float* out = (float*)d_out;

    char* ws = (char*)d_ws;
    int*   seg_start = (int*)ws;                                        // (B+1) ints
    int*   work_ctr  = (int*)(ws + 12288);                              // 1 int (reset by k_anchor3)
    float* feat_v    = (float*)(ws + 16384);                            // B*D floats (2 MB, transposed)
    float* e_buf     = (float*)(ws + 16384 + (size_t)B * D * 4);        // NN floats (400 KB)
    float* anc_buf   = (float*)(ws + 16384 + (size_t)B * D * 4 + 512 * 1024); // B*D floats (2 MB)

    k_anchor3<<<B, 256, 0, stream>>>(ifeat, seg, out, anc_buf, seg_start, work_ctr);
    k_featv3<<<B / 16, 256, 0, stream>>>(anc_buf, Wv, bv, feat_v);
    k_attn_e_mfma<<<256, 512, 0, stream>>>(ifeat, Wu, feat_v, we, seg, e_buf, work_ctr);
    k_softmax_rst<<<B, 256, 0, stream>>>(ifeat, seg_start, e_buf, out);
}

// Round 30
// 93.871 us; speedup vs baseline: 1.5931x; 1.5931x over previous
//
#include <hip/hip_runtime.h>
#include <math.h>

#define NN 102400
#define D 256
#define B 2048

typedef __bf16 bf16x8 __attribute__((ext_vector_type(8)));
typedef float f32x4 __attribute__((ext_vector_type(4)));

// K1: anchor + own bounds. Measured 15.7us/pass (R23 x8) = 6.4 TB/s — at roofline.
__global__ __launch_bounds__(256)
void k_anchor3(const float* __restrict__ ifeat, const int* __restrict__ seg,
               float* __restrict__ out, float* __restrict__ anc_buf,
               int* __restrict__ seg_start) {
    __shared__ int sb[2];
    __shared__ float red[4][256];
    int b = blockIdx.x;
    int t = threadIdx.x;
    if (t < 2) {
        int target = b + t;
        int lo = 0, hi = NN;
        while (lo < hi) { int mid = (lo + hi) >> 1; if (seg[mid] < target) lo = mid + 1; else hi = mid; }
        sb[t] = lo;
        if (t == 0) seg_start[b] = lo;
        if (t == 1 && b == B - 1) seg_start[B] = lo;
    }
    __syncthreads();
    int w = t >> 6, l = t & 63;
    int s = sb[0], e = sb[1];
    const float* bp = ifeat + (size_t)l * 4;
    float4 a0 = make_float4(0.f, 0.f, 0.f, 0.f), a1 = a0, a2 = a0, a3 = a0, a4 = a0, a5 = a0;
    int i = s + w;
    for (; i + 20 < e; i += 24) {
        float4 v0 = *(const float4*)(bp + (size_t)(i +  0) * D);
        float4 v1 = *(const float4*)(bp + (size_t)(i +  4) * D);
        float4 v2 = *(const float4*)(bp + (size_t)(i +  8) * D);
        float4 v3 = *(const float4*)(bp + (size_t)(i + 12) * D);
        float4 v4 = *(const float4*)(bp + (size_t)(i + 16) * D);
        float4 v5 = *(const float4*)(bp + (size_t)(i + 20) * D);
        a0.x += v0.x; a0.y += v0.y; a0.z += v0.z; a0.w += v0.w;
        a1.x += v1.x; a1.y += v1.y; a1.z += v1.z; a1.w += v1.w;
        a2.x += v2.x; a2.y += v2.y; a2.z += v2.z; a2.w += v2.w;
        a3.x += v3.x; a3.y += v3.y; a3.z += v3.z; a3.w += v3.w;
        a4.x += v4.x; a4.y += v4.y; a4.z += v4.z; a4.w += v4.w;
        a5.x += v5.x; a5.y += v5.y; a5.z += v5.z; a5.w += v5.w;
    }
    for (; i < e; i += 4) {
        float4 v = *(const float4*)(bp + (size_t)i * D);
        a0.x += v.x; a0.y += v.y; a0.z += v.z; a0.w += v.w;
    }
    float4 acc = make_float4(((a0.x + a1.x) + (a2.x + a3.x)) + (a4.x + a5.x),
                             ((a0.y + a1.y) + (a2.y + a3.y)) + (a4.y + a5.y),
                             ((a0.z + a1.z) + (a2.z + a3.z)) + (a4.z + a5.z),
                             ((a0.w + a1.w) + (a2.w + a3.w)) + (a4.w + a5.w));
    *(float4*)&red[w][l * 4] = acc;
    __syncthreads();
    float sum = (red[0][t] + red[1][t]) + (red[2][t] + red[3][t]);
    int cnt = e - s;
    float inv = 1.0f / (float)(cnt > 0 ? cnt : 1);
    float v = sum * inv;
    out[(size_t)b * 512 + 256 + t] = v;
    anc_buf[(size_t)b * D + t] = v;
}

// K2 (MFMA featv): writes feat_v TRANSPOSED (R24): fvT[seg*256 + (j&15)*16 + (j>>4)].
__global__ __launch_bounds__(256)
void k_featv3(const float* __restrict__ anc_buf, const float* __restrict__ Wv,
              const float* __restrict__ bv, float* __restrict__ fvT) {
    __shared__ __bf16 As[16][264];   // 256 + 8 pad
    int b0 = blockIdx.x * 16;
    int t = threadIdx.x;
    int lane = t & 63, w = t >> 6;
    int ln15 = lane & 15, lg = lane >> 4;
#pragma unroll
    for (int r = 0; r < 16; ++r) As[r][t] = (__bf16)anc_buf[(size_t)(b0 + r) * D + t];
    __syncthreads();
    bf16x8 afr[8];
#pragma unroll
    for (int kc = 0; kc < 8; ++kc) afr[kc] = *(const bf16x8*)&As[ln15][kc * 32 + lg * 8];
#pragma unroll
    for (int q = 0; q < 4; ++q) {
        int jt = w * 4 + q;                   // j = jt*16 + ln15
        f32x4 acc = (f32x4){0.f, 0.f, 0.f, 0.f};
#pragma unroll
        for (int kc = 0; kc < 8; ++kc) {
            const float* wp = Wv + (size_t)(jt * 16 + ln15) * D + kc * 32 + lg * 8;
            float4 p = *(const float4*)(wp);
            float4 r4 = *(const float4*)(wp + 4);
            bf16x8 bfr;
            bfr[0] = (__bf16)p.x;  bfr[1] = (__bf16)p.y;  bfr[2] = (__bf16)p.z;  bfr[3] = (__bf16)p.w;
            bfr[4] = (__bf16)r4.x; bfr[5] = (__bf16)r4.y; bfr[6] = (__bf16)r4.z; bfr[7] = (__bf16)r4.w;
            acc = __builtin_amdgcn_mfma_f32_16x16x32_bf16(afr[kc], bfr, acc, 0, 0, 0);
        }
        float bvj = bv[jt * 16 + ln15];
#pragma unroll
        for (int r = 0; r < 4; ++r) {
            fvT[(size_t)(b0 + lg * 4 + r) * 256 + ln15 * 16 + jt] = acc[r] + bvj;
        }
    }
}

// K3 (MFMA attn, R30 = R28 FINAL): 512 thr / 1 block/CU (256-reg unified cap),
// fv-transposed prefetch (R24, +7us), 3-deep rolling A pipeline (R26),
// setprio around MFMA cluster (R27, -2us), balanced static item map (R28, -4.5us).
// R29 lesson: end-of-item atomic work-stealing serializes the next item's
// prefetch behind a ~500-900cyc atomic round-trip AND kills cross-item
// software pipelining — static balanced map is the optimum here.
__global__ __launch_bounds__(512, 1)
void k_attn_e_mfma(const float* __restrict__ ifeat, const float* __restrict__ Wu,
                   const float* __restrict__ fvT, const float* __restrict__ we,
                   const int* __restrict__ seg_ids, float* __restrict__ e_out) {
    __shared__ __bf16 Bs[256 * 256];   // 128 KB; row j stride 512 B; byte ^= (j&7)<<4

    int tx = threadIdx.x;
    int lane = tx & 63;
    int w = tx >> 6;                   // 0..7
    int ln15 = lane & 15;
    int lg = lane >> 4;

    // ---- stage full Wu: thread -> (row jl=tx>>1, k-half kh=tx&1), 128 elems ----
    {
        int jl = tx >> 1, kh = tx & 1;
        const float* wp = Wu + (size_t)jl * D + kh * 128;
        char* rowp = (char*)Bs + jl * 512;
        int sw = (jl & 7) << 4;
#pragma unroll
        for (int q = 0; q < 16; ++q) {
            float4 b0 = *(const float4*)(wp + q * 8);
            float4 b1 = *(const float4*)(wp + q * 8 + 4);
            bf16x8 v;
            v[0] = (__bf16)b0.x; v[1] = (__bf16)b0.y; v[2] = (__bf16)b0.z; v[3] = (__bf16)b0.w;
            v[4] = (__bf16)b1.x; v[5] = (__bf16)b1.y; v[6] = (__bf16)b1.z; v[7] = (__bf16)b1.w;
            *(bf16x8*)(rowp + ((kh * 256 + q * 16) ^ sw)) = v;
        }
    }
    __syncthreads();

    int swr = (ln15 & 7) << 4;
    int klo = lg * 16;
    const char* bbase = (const char*)Bs + ln15 * 512;
    const float* weh  = we + ln15;

    int wgid = blockIdx.x + 256 * w;         // balanced static item map

    for (int item = wgid; item < NN / 16; item += 2048) {
        int nb = item * 16;
        int r0 = nb + lg * 4;

        // ---- prefetch epilogue fv: 4 rows x 4 float4 (transposed layout) ----
        const float* q0 = fvT + (size_t)seg_ids[r0 + 0] * 256 + ln15 * 16;
        const float* q1 = fvT + (size_t)seg_ids[r0 + 1] * 256 + ln15 * 16;
        const float* q2 = fvT + (size_t)seg_ids[r0 + 2] * 256 + ln15 * 16;
        const float* q3 = fvT + (size_t)seg_ids[r0 + 3] * 256 + ln15 * 16;
        float4 fvA0 = *(const float4*)(q0 +  0), fvA1 = *(const float4*)(q0 +  4),
               fvA2 = *(const float4*)(q0 +  8), fvA3 = *(const float4*)(q0 + 12);
        float4 fvB0 = *(const float4*)(q1 +  0), fvB1 = *(const float4*)(q1 +  4),
               fvB2 = *(const float4*)(q1 +  8), fvB3 = *(const float4*)(q1 + 12);
        float4 fvC0 = *(const float4*)(q2 +  0), fvC1 = *(const float4*)(q2 +  4),
               fvC2 = *(const float4*)(q2 +  8), fvC3 = *(const float4*)(q2 + 12);
        float4 fvD0 = *(const float4*)(q3 +  0), fvD1 = *(const float4*)(q3 +  4),
               fvD2 = *(const float4*)(q3 +  8), fvD3 = *(const float4*)(q3 + 12);

        const float* ap = ifeat + (size_t)(nb + ln15) * D + lg * 8;

        f32x4 a0 = (f32x4){0.f,0.f,0.f,0.f}, a1 = a0, a2 = a0, a3 = a0,
              a4 = a0, a5 = a0, a6 = a0, a7 = a0,
              a8 = a0, a9 = a0, a10 = a0, a11 = a0,
              a12 = a0, a13 = a0, a14 = a0, a15 = a0;

        // ---- 3-deep rolling A pipeline (named regs, static indices) ----
        float4 xc = *(const float4*)(ap +  0), yc = *(const float4*)(ap +  4);
        float4 x1 = *(const float4*)(ap + 32), y1 = *(const float4*)(ap + 36);
        float4 x2 = *(const float4*)(ap + 64), y2 = *(const float4*)(ap + 68);
#pragma unroll 1
        for (int ch = 0; ch < 8; ++ch) {
            int nx = ((ch + 3) & 7) * 32;              // wrap: last 3 iters re-read 0..2 (L1-hot)
            float4 x3 = *(const float4*)(ap + nx);
            float4 y3 = *(const float4*)(ap + nx + 4);
            bf16x8 af;
            af[0] = (__bf16)xc.x; af[1] = (__bf16)xc.y; af[2] = (__bf16)xc.z; af[3] = (__bf16)xc.w;
            af[4] = (__bf16)yc.x; af[5] = (__bf16)yc.y; af[6] = (__bf16)yc.z; af[7] = (__bf16)yc.w;
            int kb = (ch * 64 + klo) ^ swr;
            __builtin_amdgcn_s_setprio(1);
            a0  = __builtin_amdgcn_mfma_f32_16x16x32_bf16(af, *(const bf16x8*)(bbase +  0 * 8192 + kb), a0,  0, 0, 0);
            a1  = __builtin_amdgcn_mfma_f32_16x16x32_bf16(af, *(const bf16x8*)(bbase +  1 * 8192 + kb), a1,  0, 0, 0);
            a2  = __builtin_amdgcn_mfma_f32_16x16x32_bf16(af, *(const bf16x8*)(bbase +  2 * 8192 + kb), a2,  0, 0, 0);
            a3  = __builtin_amdgcn_mfma_f32_16x16x32_bf16(af, *(const bf16x8*)(bbase +  3 * 8192 + kb), a3,  0, 0, 0);
            a4  = __builtin_amdgcn_mfma_f32_16x16x32_bf16(af, *(const bf16x8*)(bbase +  4 * 8192 + kb), a4,  0, 0, 0);
            a5  = __builtin_amdgcn_mfma_f32_16x16x32_bf16(af, *(const bf16x8*)(bbase +  5 * 8192 + kb), a5,  0, 0, 0);
            a6  = __builtin_amdgcn_mfma_f32_16x16x32_bf16(af, *(const bf16x8*)(bbase +  6 * 8192 + kb), a6,  0, 0, 0);
            a7  = __builtin_amdgcn_mfma_f32_16x16x32_bf16(af, *(const bf16x8*)(bbase +  7 * 8192 + kb), a7,  0, 0, 0);
            a8  = __builtin_amdgcn_mfma_f32_16x16x32_bf16(af, *(const bf16x8*)(bbase +  8 * 8192 + kb), a8,  0, 0, 0);
            a9  = __builtin_amdgcn_mfma_f32_16x16x32_bf16(af, *(const bf16x8*)(bbase +  9 * 8192 + kb), a9,  0, 0, 0);
            a10 = __builtin_amdgcn_mfma_f32_16x16x32_bf16(af, *(const bf16x8*)(bbase + 10 * 8192 + kb), a10, 0, 0, 0);
            a11 = __builtin_amdgcn_mfma_f32_16x16x32_bf16(af, *(const bf16x8*)(bbase + 11 * 8192 + kb), a11, 0, 0, 0);
            a12 = __builtin_amdgcn_mfma_f32_16x16x32_bf16(af, *(const bf16x8*)(bbase + 12 * 8192 + kb), a12, 0, 0, 0);
            a13 = __builtin_amdgcn_mfma_f32_16x16x32_bf16(af, *(const bf16x8*)(bbase + 13 * 8192 + kb), a13, 0, 0, 0);
            a14 = __builtin_amdgcn_mfma_f32_16x16x32_bf16(af, *(const bf16x8*)(bbase + 14 * 8192 + kb), a14, 0, 0, 0);
            a15 = __builtin_amdgcn_mfma_f32_16x16x32_bf16(af, *(const bf16x8*)(bbase + 15 * 8192 + kb), a15, 0, 0, 0);
            __builtin_amdgcn_s_setprio(0);
            xc = x1; yc = y1; x1 = x2; y1 = y2; x2 = x3; y2 = y3;
        }

        float part0 = 0.f, part1 = 0.f, part2 = 0.f, part3 = 0.f;

#define EPI(AC, CT, FQ, FC) { \
    float w_ = weh[(CT) * 16]; \
    part0 += w_ * __builtin_amdgcn_rcpf(1.f + __expf(-(AC[0] + fvA##FQ.FC))); \
    part1 += w_ * __builtin_amdgcn_rcpf(1.f + __expf(-(AC[1] + fvB##FQ.FC))); \
    part2 += w_ * __builtin_amdgcn_rcpf(1.f + __expf(-(AC[2] + fvC##FQ.FC))); \
    part3 += w_ * __builtin_amdgcn_rcpf(1.f + __expf(-(AC[3] + fvD##FQ.FC))); }

        EPI(a0,  0, 0, x) EPI(a1,  1, 0, y) EPI(a2,  2, 0, z) EPI(a3,  3, 0, w)
        EPI(a4,  4, 1, x) EPI(a5,  5, 1, y) EPI(a6,  6, 1, z) EPI(a7,  7, 1, w)
        EPI(a8,  8, 2, x) EPI(a9,  9, 2, y) EPI(a10, 10, 2, z) EPI(a11, 11, 2, w)
        EPI(a12, 12, 3, x) EPI(a13, 13, 3, y) EPI(a14, 14, 3, z) EPI(a15, 15, 3, w)
#undef EPI

#pragma unroll
        for (int off = 8; off >= 1; off >>= 1) {
            part0 += __shfl_xor(part0, off, 64);
            part1 += __shfl_xor(part1, off, 64);
            part2 += __shfl_xor(part2, off, 64);
            part3 += __shfl_xor(part3, off, 64);
        }
        if (ln15 == 0) {
            float4 o = make_float4(part0, part1, part2, part3);
            *(float4*)&e_out[r0] = o;
        }
    }
}

// K4: segment softmax + weighted sum. UNCHANGED.
__global__ void k_softmax_rst(const float* __restrict__ ifeat, const int* __restrict__ seg_start,
                              const float* __restrict__ e, float* __restrict__ out) {
    int b = blockIdx.x;
    int t = threadIdx.x; // 256
    int w = t >> 6, l = t & 63;
    int s = seg_start[b], en = seg_start[b + 1];
    float m = -1e30f;
    for (int i = s + t; i < en; i += 256) m = fmaxf(m, e[i]);
#pragma unroll
    for (int off = 32; off >= 1; off >>= 1) m = fmaxf(m, __shfl_xor(m, off, 64));
    __shared__ float red[4];
    if ((t & 63) == 0) red[t >> 6] = m;
    __syncthreads();
    float mall = fmaxf(fmaxf(red[0], red[1]), fmaxf(red[2], red[3]));
    float dsum = 0.f;
    for (int i = s + t; i < en; i += 256) dsum += __expf(e[i] - mall);
#pragma unroll
    for (int off = 32; off >= 1; off >>= 1) dsum += __shfl_xor(dsum, off, 64);
    __shared__ float red2[4];
    if ((t & 63) == 0) red2[t >> 6] = dsum;
    __syncthreads();
    float denom = red2[0] + red2[1] + red2[2] + red2[3];
    float invd = (en > s) ? 1.0f / denom : 0.f;

    const float* bp = ifeat + (size_t)l * 4;
    float4 c0 = make_float4(0.f, 0.f, 0.f, 0.f), c1 = c0, c2 = c0, c3 = c0, c4 = c0, c5 = c0;
    int i = s + w;
    for (; i + 20 < en; i += 24) {
        float al0 = __expf(e[i +  0] - mall) * invd;
        float al1 = __expf(e[i +  4] - mall) * invd;
        float al2 = __expf(e[i +  8] - mall) * invd;
        float al3 = __expf(e[i + 12] - mall) * invd;
        float al4 = __expf(e[i + 16] - mall) * invd;
        float al5 = __expf(e[i + 20] - mall) * invd;
        float4 v0 = *(const float4*)(bp + (size_t)(i +  0) * D);
        float4 v1 = *(const float4*)(bp + (size_t)(i +  4) * D);
        float4 v2 = *(const float4*)(bp + (size_t)(i +  8) * D);
        float4 v3 = *(const float4*)(bp + (size_t)(i + 12) * D);
        float4 v4 = *(const float4*)(bp + (size_t)(i + 16) * D);
        float4 v5 = *(const float4*)(bp + (size_t)(i + 20) * D);
        c0.x += v0.x * al0; c0.y += v0.y * al0; c0.z += v0.z * al0; c0.w += v0.w * al0;
        c1.x += v1.x * al1; c1.y += v1.y * al1; c1.z += v1.z * al1; c1.w += v1.w * al1;
        c2.x += v2.x * al2; c2.y += v2.y * al2; c2.z += v2.z * al2; c2.w += v2.w * al2;
        c3.x += v3.x * al3; c3.y += v3.y * al3; c3.z += v3.z * al3; c3.w += v3.w * al3;
        c4.x += v4.x * al4; c4.y += v4.y * al4; c4.z += v4.z * al4; c4.w += v4.w * al4;
        c5.x += v5.x * al5; c5.y += v5.y * al5; c5.z += v5.z * al5; c5.w += v5.w * al5;
    }
    for (; i < en; i += 4) {
        float al = __expf(e[i] - mall) * invd;
        float4 v = *(const float4*)(bp + (size_t)i * D);
        c0.x += v.x * al; c0.y += v.y * al; c0.z += v.z * al; c0.w += v.w * al;
    }
    float4 acc = make_float4(((c0.x + c1.x) + (c2.x + c3.x)) + (c4.x + c5.x),
                             ((c0.y + c1.y) + (c2.y + c3.y)) + (c4.y + c5.y),
                             ((c0.z + c1.z) + (c2.z + c3.z)) + (c4.z + c5.z),
                             ((c0.w + c1.w) + (c2.w + c3.w)) + (c4.w + c5.w));
    __shared__ float red3[4][256];
    *(float4*)&red3[w][l * 4] = acc;
    __syncthreads();
    out[(size_t)b * 512 + t] = (red3[0][t] + red3[1][t]) + (red3[2][t] + red3[3][t]);
}

extern "C" void kernel_launch(void* const* d_in, const int* in_sizes, int n_in,
                              void* d_out, int out_size, void* d_ws, size_t ws_size,
                              hipStream_t stream) {
    const float* ifeat = (const float*)d_in[0];
    const float* Wu    = (const float*)d_in[1];
    const float* Wv    = (const float*)d_in[2];
    const float* bv    = (const float*)d_in[3];
    const float* we    = (const float*)d_in[4];
    const int*   seg   = (const int*)d_in[5];
    float* out = (float*)d_out;

    char* ws = (char*)d_ws;
    int*   seg_start = (int*)ws;                                        // (B+1) ints
    float* feat_v    = (float*)(ws + 16384);                            // B*D floats (2 MB, transposed)
    float* e_buf     = (float*)(ws + 16384 + (size_t)B * D * 4);        // NN floats (400 KB)
    float* anc_buf   = (float*)(ws + 16384 + (size_t)B * D * 4 + 512 * 1024); // B*D floats (2 MB)

    k_anchor3<<<B, 256, 0, stream>>>(ifeat, seg, out, anc_buf, seg_start);
    k_featv3<<<B / 16, 256, 0, stream>>>(anc_buf, Wv, bv, feat_v);
    k_attn_e_mfma<<<256, 512, 0, stream>>>(ifeat, Wu, feat_v, we, seg, e_buf);
    k_softmax_rst<<<B, 256, 0, stream>>>(ifeat, seg_start, e_buf, out);
}